// Round 1
// baseline (156.099 us; speedup 1.0000x reference)
//
#include <hip/hip_runtime.h>

// B=64, H=W=32, HW=1024, steps<=256, backtrack 255.
// Outputs: [histories 65536][paths 65536][pred_cost 65536] float32.
// Single fused kernel: 64 blocks (1 per batch) x 256 threads.
//   Phase 1 (all 256 thr): conv1(2->32)+ReLU, conv2(32->1)+sigmoid.
//            (unchanged, bit-identical accumulation order).
//   Phase 2 (wave 0 only): A* with FULLY REGISTER-RESIDENT state.
//            Lane owns cells {j*64+lane}; candidate cells cA/cB are always
//            lane-owned (row parity == half), and all per-step register
//            indices lie in the uniform pair {j0, j0+1}, j0=(ys-1)>>1.
//            vkey/g/h/c live in per-lane reg arrays; extraction and update
//            go through compile-time-unrolled uniform branches (no dynamic
//            reg indexing -> no scratch). g[sel]/c[sel] via uniform-switch
//            extract + v_readlane from owner. par stays in LDS (write-only
//            in loop). This removes BOTH per-step LDS latency windows
//            (~300 cy of a ~950 cy serial chain).
//            FREEZE BREAK: ballot==0 => fixed point => exact early exit.
//   Phase 3 (all): backtrack (lane 0) + output writes.

#define HW 1024

// DPP wave-64 max-reduce step on a u64 key (hi=value bits, lo=1023-cell).
#define DPP_MAX64(key, ctrl) do {                                              \
    unsigned int _lo = (unsigned int)(key);                                    \
    unsigned int _hi = (unsigned int)((key) >> 32);                            \
    unsigned int _slo = (unsigned int)__builtin_amdgcn_update_dpp(             \
        (int)_lo, (int)_lo, (ctrl), 0xf, 0xf, false);                          \
    unsigned int _shi = (unsigned int)__builtin_amdgcn_update_dpp(             \
        (int)_hi, (int)_hi, (ctrl), 0xf, 0xf, false);                          \
    unsigned long long _o = ((unsigned long long)_shi << 32) | _slo;           \
    if (_o > (key)) (key) = _o;                                                \
} while (0)

__global__ __launch_bounds__(256) void fused_nastar(
    const float* __restrict__ maps, const float* __restrict__ start,
    const float* __restrict__ goal, const float* __restrict__ w1,
    const float* __restrict__ b1, const float* __restrict__ w2,
    const float* __restrict__ b2, float* __restrict__ out_hist,
    float* __restrict__ out_path, float* __restrict__ out_cost) {
  __shared__ float hid[8][HW];            // 32 KB
  __shared__ float c_l[HW];               // 4 KB: cost (phase1 -> wave0 xfer)
  __shared__ unsigned short par[HW];      // 2 KB
  __shared__ unsigned char path_sh[HW];   // 1 KB
  __shared__ unsigned int hist_lds[64];   // 256 B
  // ~39.3 KB

  const int t = threadIdx.x;
  const int b = blockIdx.x;
  const float C_INV = 0.17677669529663687f;  // float32(1/sqrt(32))

  const float* m_p = maps  + b * HW;
  const float* s_p = start + b * HW;
  const float* g_p = goal  + b * HW;

  // ---------------- Phase 1: encoder (lane-contiguous pixel map) -----------
  float acc2[4] = {b2[0], b2[0], b2[0], b2[0]};
  for (int grp = 0; grp < 4; ++grp) {
    #pragma unroll
    for (int p = 0; p < 4; ++p) {
      int pix = p * 256 + t;
      int y = pix >> 5, x = pix & 31;
      float win0[9], win1[9];
      #pragma unroll
      for (int ky = 0; ky < 3; ++ky) {
        #pragma unroll
        for (int kx = 0; kx < 3; ++kx) {
          int yy = y + ky - 1, xx = x + kx - 1;
          bool ok = (yy >= 0) && (yy <= 31) && (xx >= 0) && (xx <= 31);
          int q = ok ? yy * 32 + xx : 0;
          float v0 = m_p[q];
          float v1 = s_p[q] + g_p[q];
          win0[ky * 3 + kx] = ok ? v0 : 0.0f;
          win1[ky * 3 + kx] = ok ? v1 : 0.0f;
        }
      }
      #pragma unroll
      for (int ocl = 0; ocl < 8; ++ocl) {
        int oc = grp * 8 + ocl;
        const float* w = w1 + oc * 18;
        float acc = b1[oc];
        #pragma unroll
        for (int k = 0; k < 9; ++k) {
          acc += win0[k] * w[k];       // same per-pixel op order as round 1
          acc += win1[k] * w[9 + k];
        }
        hid[ocl][pix] = fmaxf(acc, 0.0f);
      }
    }
    __syncthreads();
    #pragma unroll
    for (int p = 0; p < 4; ++p) {
      int pix = p * 256 + t;
      int y = pix >> 5, x = pix & 31;
      float a = acc2[p];
      #pragma unroll
      for (int ocl = 0; ocl < 8; ++ocl) {
        int ic = grp * 8 + ocl;
        const float* w = w2 + ic * 9;
        #pragma unroll
        for (int ky = 0; ky < 3; ++ky) {
          #pragma unroll
          for (int kx = 0; kx < 3; ++kx) {
            int yy = y + ky - 1, xx = x + kx - 1;
            bool ok = (yy >= 0) && (yy <= 31) && (xx >= 0) && (xx <= 31);
            int q = ok ? yy * 32 + xx : 0;
            float hv = hid[ocl][q];
            a += (ok ? hv : 0.0f) * w[ky * 3 + kx];
          }
        }
      }
      acc2[p] = a;
    }
    __syncthreads();
  }
  #pragma unroll
  for (int p = 0; p < 4; ++p) {
    int pix = p * 256 + t;
    float c = 1.0f / (1.0f + expf(-acc2[p]));
    c_l[pix] = c;
    out_cost[b * HW + pix] = c;          // stride-1 across lanes: coalesced
  }
  __syncthreads();

  // ---------------- Phase 2: A* (wave 0, all-register state) ---------------
  if (t < 64) {
    const int lane = t;
    reinterpret_cast<int4*>(path_sh)[lane] = make_int4(0, 0, 0, 0);
    // goal via ballot (one-hot)
    int myg = -1;
    #pragma unroll
    for (int j = 0; j < 16; ++j) {
      int cell = j * 64 + lane;
      if (g_p[cell] > 0.5f) myg = cell;
    }
    unsigned long long gm = __ballot(myg >= 0);
    int src_lane = (int)__ffsll(gm) - 1;
    const int goal_idx = __shfl(myg, src_lane, 64);
    const int gy = goal_idx >> 5, gx = goal_idx & 31;

    unsigned int open_m = 0, hist_m = 0, obs_m = 0;
    float gr[16], hr[16], cr[16];
    unsigned int vr[16];
    #pragma unroll
    for (int j = 0; j < 16; ++j) {
      int cell = j * 64 + lane;
      int y = cell >> 5, x = cell & 31;
      float cst = c_l[cell];
      cr[j] = cst;
      int dy = y - gy; dy = dy < 0 ? -dy : dy;
      int dx = x - gx; dx = dx < 0 ? -dx : dx;
      float e = sqrtf((float)(dy * dy + dx * dx));
      float heur = __fadd_rn((float)(dy + dx), __fmul_rn(0.001f, e));
      float hc = __fadd_rn(heur, cst);       // h4 = heuristic + cost
      hr[j] = hc;
      gr[j] = 0.0f;
      bool isobs = (m_p[cell] != 0.0f);
      bool isst  = (s_p[cell] > 0.5f);
      if (isobs) obs_m  |= 1u << j;
      if (isst)  open_m |= 1u << j;
      float f = 0.5f * (0.0f + hc);
      float ex = expf(__fmul_rn(-f, C_INV));
      vr[j] = isst ? __float_as_uint(ex) : 0u;
      par[cell] = (unsigned short)goal_idx;
    }

    const int x = lane & 31, half = lane >> 5;
    const unsigned int lowbase = 1023u - (unsigned)lane;  // lo = lowbase - 64j

    for (int step = 0; step < 256; ++step) {
      // local 16->1 argmax over registers (value compare; ties -> smaller j,
      // identical to u64 key compare since lo decreases with j)
      unsigned int tv[8], tj[8];
      #pragma unroll
      for (int i = 0; i < 8; ++i) {
        bool gt2 = vr[i + 8] > vr[i];
        tv[i] = gt2 ? vr[i + 8] : vr[i];
        tj[i] = gt2 ? (unsigned)(i + 8) : (unsigned)i;
      }
      #pragma unroll
      for (int s = 4; s >= 1; s >>= 1) {
        #pragma unroll
        for (int i = 0; i < s; ++i)
          if (tv[i + s] > tv[i]) { tv[i] = tv[i + s]; tj[i] = tj[i + s]; }
      }
      unsigned long long key = ((unsigned long long)tv[0] << 32) |
                               (unsigned long long)(lowbase - (tj[0] << 6));
      DPP_MAX64(key, 0x111);  // row_shr:1
      DPP_MAX64(key, 0x112);  // row_shr:2
      DPP_MAX64(key, 0x114);  // row_shr:4
      DPP_MAX64(key, 0x118);  // row_shr:8
      DPP_MAX64(key, 0x142);  // row_bcast:15
      DPP_MAX64(key, 0x143);  // row_bcast:31
      unsigned int klo =
          (unsigned int)__builtin_amdgcn_readlane((int)(unsigned int)key, 63);
      const int sel = __builtin_amdgcn_readfirstlane(1023 - (int)klo);
      const int jsel = sel >> 6, owner = sel & 63;
      const int ys = sel >> 5, xs = sel & 31;
      const bool unsolved = (sel != goal_idx);

      // uniform register-index pair touched this step: {j0, j1u}
      const int j0  = (ys > 0 ? ys - 1 : 0) >> 1;       // == jM
      const int j1u = (j0 < 15) ? j0 + 1 : 15;
      const int jP  = (ys < 31 ? ys + 1 : 31) >> 1;     // B-candidate index
      const bool jS_is_j0 = (jsel == j0);
      const bool jP_is_j0 = (jP == j0);

      // uniform-switch extraction (j0 is SGPR -> scalar branches, no scratch)
      float gj0 = 0.f, hj0 = 0.f, cj0 = 0.f, gj1 = 0.f, hj1 = 0.f, cj1 = 0.f;
      #pragma unroll
      for (int j = 0; j < 16; ++j) {
        if (j0 == j) {
          const int jn = (j < 15) ? j + 1 : 15;
          gj0 = gr[j];  hj0 = hr[j];  cj0 = cr[j];
          gj1 = gr[jn]; hj1 = hr[jn]; cj1 = cr[jn];
        }
      }

      // uniform reads of the selected cell via owner-lane readlane
      float gselv = jS_is_j0 ? gj0 : gj1;
      float cselv = jS_is_j0 ? cj0 : cj1;
      float gs = __uint_as_float((unsigned int)__builtin_amdgcn_readlane(
          (int)__float_as_uint(gselv), owner));
      float cs = __uint_as_float((unsigned int)__builtin_amdgcn_readlane(
          (int)__float_as_uint(cselv), owner));
      const float gsum = gs + cs;            // g2 value (exact, as reference)

      // candidate geometry (candidates are always lane-owned cells)
      int dxs = x - xs; int adx = dxs < 0 ? -dxs : dxs;
      const bool act = (adx <= 1);
      const bool samep = (((ys ^ half) & 1) == 0);
      const int yA = samep ? ys : (ys - 1);
      const bool vAv = act && (samep ? (adx >= 1) : (yA >= 0));
      const int yB = ys + 1;
      const bool vBv = act && (!samep) && (yB <= 31);
      const int cA = vAv ? (yA * 32 + x) : 0;
      const int cB = vBv ? (yB * 32 + x) : 0;

      const bool vjA_is_j0 = (!samep) || jS_is_j0;   // vjA in {j0, j1u}
      const int vjA = samep ? jsel : j0;             // A-candidate reg index
      float gA = vjA_is_j0 ? gj0 : gj1;
      float hA = vjA_is_j0 ? hj0 : hj1;
      float gB = jP_is_j0 ? gj0 : gj1;
      float hB = jP_is_j0 ? hj0 : hj1;

      bool obA = (obs_m  >> (vjA & 15)) & 1;
      bool opA = (open_m >> (vjA & 15)) & 1;
      bool hiA = (hist_m >> (vjA & 15)) & 1;
      bool obB = (obs_m  >> (jP & 15)) & 1;
      bool opB = (open_m >> (jP & 15)) & 1;
      bool hiB = (hist_m >> (jP & 15)) & 1;

      const bool idxA = vAv && obA && ((!opA && !hiA) || (opA && (gA > gsum)));
      const bool idxB = vBv && obB && ((!opB && !hiB) || (opB && (gB > gsum)));
      const bool ownerlane = (lane == owner);
      const bool closeU = unsolved && ownerlane;

      // change detection (pre-update bits)
      const bool histnew = ownerlane && !((hist_m >> (jsel & 15)) & 1);
      const bool opencl  = closeU && ((open_m >> (jsel & 15)) & 1);

      // mask updates
      hist_m |= ownerlane ? (1u << (jsel & 15)) : 0u;
      unsigned int clr = closeU ? (1u << (jsel & 15)) : 0u;
      unsigned int aA  = idxA ? (1u << (vjA & 15)) : 0u;
      unsigned int aB  = idxB ? (1u << (jP & 15)) : 0u;
      open_m = (open_m & ~clr) | aA | aB;

      // new key values (identical FP sequence to previous rounds)
      float fA = 0.5f * (gsum + hA);
      unsigned int nvA = __float_as_uint(expf(__fmul_rn(-fA, C_INV)));
      float fB = 0.5f * (gsum + hB);
      unsigned int nvB = __float_as_uint(expf(__fmul_rn(-fB, C_INV)));

      // par stays in LDS: write-only inside the loop, never waited on
      if (idxA) par[cA] = (unsigned short)sel;
      if (idxB) par[cB] = (unsigned short)sel;

      // uniform-switch register updates (only j0 / j1u can change)
      #pragma unroll
      for (int j = 0; j < 16; ++j) {
        const bool hit = (j == j0) || (j == j1u);
        if (hit) {
          const bool atlo = (j == j0);                 // uniform
          const bool uA = idxA && (vjA_is_j0 == atlo); // per-lane
          const bool uB = idxB && (jP_is_j0 == atlo);
          const bool uu = uA || uB;
          if (uu) gr[j] = gsum;
          unsigned int nv = uA ? nvA : nvB;
          if (uu) vr[j] = nv;
          if (j == jsel) {                             // uniform
            if (closeU) vr[j] = 0u;                    // close selected cell
          }
        }
      }

      // freeze: nothing changed => fixed point => all remaining steps no-ops
      unsigned long long anych = __ballot(idxA || idxB || histnew || opencl);
      if (anych == 0ull) break;
    }

    hist_lds[lane] = hist_m;

    // backtrack (parent table static; revisit => cycle => exact early exit)
    if (lane == 0) {
      path_sh[goal_idx] = 1;
      int loc = par[goal_idx];
      for (int i = 0; i < 255; ++i) {
        if (path_sh[loc]) break;
        path_sh[loc] = 1;
        loc = par[loc];
      }
    }
  }
  __syncthreads();

  // ---------------- Phase 3: outputs ----------------
  const int base = t * 4;
  float hv[4], pv[4];
  #pragma unroll
  for (int p = 0; p < 4; ++p) {
    int cell = base + p;
    hv[p] = (float)((hist_lds[cell & 63] >> (cell >> 6)) & 1);
    pv[p] = (float)path_sh[cell];
  }
  *reinterpret_cast<float4*>(out_hist + b * HW + base) =
      make_float4(hv[0], hv[1], hv[2], hv[3]);
  *reinterpret_cast<float4*>(out_path + b * HW + base) =
      make_float4(pv[0], pv[1], pv[2], pv[3]);
}

extern "C" void kernel_launch(void* const* d_in, const int* in_sizes, int n_in,
                              void* d_out, int out_size, void* d_ws, size_t ws_size,
                              hipStream_t stream) {
  (void)in_sizes; (void)n_in; (void)d_ws; (void)ws_size; (void)out_size;
  const float* maps  = (const float*)d_in[0];
  const float* start = (const float*)d_in[1];
  const float* goal  = (const float*)d_in[2];
  const float* w1    = (const float*)d_in[3];
  const float* b1    = (const float*)d_in[4];
  const float* w2    = (const float*)d_in[5];
  const float* b2    = (const float*)d_in[6];

  float* out      = (float*)d_out;
  float* out_hist = out;
  float* out_path = out + 64 * HW;
  float* out_cost = out + 128 * HW;

  fused_nastar<<<64, 256, 0, stream>>>(maps, start, goal, w1, b1, w2, b2,
                                       out_hist, out_path, out_cost);
}

// Round 2
// 141.369 us; speedup vs baseline: 1.1042x; 1.1042x over previous
//
#include <hip/hip_runtime.h>

// B=64, H=W=32, HW=1024, steps<=256, backtrack 255.
// Outputs: [histories 65536][paths 65536][pred_cost 65536] float32.
// Single fused kernel: 64 blocks (1 per batch) x 256 threads.
//   Phase 1 (all 256 thr): conv1(2->32)+ReLU, conv2(32->1)+sigmoid.
//            (unchanged, bit-identical accumulation order).
//   Phase 2 (wave 0 only): register-resident A* with:
//     - INCREMENTAL TOURNAMENT TREE per lane: (value,index) nodes
//       8 pairs -> 4 quads -> 2 octs -> root. All per-step register writes
//       hit regs {j0, j0+1} (j0=(ys-1)>>1, uniform), so only the 4-7 path
//       nodes are repaired inside the uniform arm (static node indices).
//       Contiguous-range tree => tie-break is exactly smallest-cell-index
//       (matches reference argmax; fixes round-1's butterfly-tree tie order).
//     - TWO-PHASE 32-bit DPP reduce: 6x v_max_u32-DPP on root value,
//       readlane, then 6x DPP max on position key (1023-cell) among
//       value-matching lanes. Replaces the u64 DPP chain.
//     - SINGLE merged 16-arm uniform switch: extraction, readlane(g,c of
//       sel), relax decisions, exp updates, register writes and tree repair
//       all inside one arm (one branch chain per step instead of two).
//     FREEZE BREAK: ballot==0 => fixed point => exact early exit.
//   Phase 3 (all): backtrack (lane 0) + output writes.

#define HW 1024

// DPP wave-64 u32 max step (compiler folds DPP into v_max_u32).
#define DPPMAX32(v, ctrl) do {                                                 \
    unsigned int _s = (unsigned int)__builtin_amdgcn_update_dpp(               \
        (int)(v), (int)(v), (ctrl), 0xf, 0xf, false);                          \
    (v) = (_s > (v)) ? _s : (v);                                               \
} while (0)

// Tournament-tree node repairs (value-only compare; tie keeps LEFT child =
// smaller index side; children cover contiguous index ranges => exact
// smallest-index tie-break).
#define PAIR_FIX(a_) { bool _r = vr[2*(a_)+1] > vr[2*(a_)];                    \
    pv[(a_)] = _r ? vr[2*(a_)+1] : vr[2*(a_)];                                 \
    pj[(a_)] = _r ? (unsigned)(2*(a_)+1) : (unsigned)(2*(a_)); }
#define QUAD_FIX(q_) { bool _r = pv[2*(q_)+1] > pv[2*(q_)];                    \
    qv[(q_)] = _r ? pv[2*(q_)+1] : pv[2*(q_)];                                 \
    qj[(q_)] = _r ? pj[2*(q_)+1] : pj[2*(q_)]; }
#define OCT_FIX(o_) { bool _r = qv[2*(o_)+1] > qv[2*(o_)];                     \
    ov[(o_)] = _r ? qv[2*(o_)+1] : qv[2*(o_)];                                 \
    oj[(o_)] = _r ? qj[2*(o_)+1] : qj[2*(o_)]; }
#define ROOT_FIX() { bool _r = ov[1] > ov[0];                                  \
    rv = _r ? ov[1] : ov[0]; rj = _r ? oj[1] : oj[0]; }

__global__ __launch_bounds__(256) void fused_nastar(
    const float* __restrict__ maps, const float* __restrict__ start,
    const float* __restrict__ goal, const float* __restrict__ w1,
    const float* __restrict__ b1, const float* __restrict__ w2,
    const float* __restrict__ b2, float* __restrict__ out_hist,
    float* __restrict__ out_path, float* __restrict__ out_cost) {
  __shared__ float hid[8][HW];            // 32 KB
  __shared__ float c_l[HW];               // 4 KB: cost (phase1 -> wave0 xfer)
  __shared__ unsigned short par[HW];      // 2 KB
  __shared__ unsigned char path_sh[HW];   // 1 KB
  __shared__ unsigned int hist_lds[64];   // 256 B

  const int t = threadIdx.x;
  const int b = blockIdx.x;
  const float C_INV = 0.17677669529663687f;  // float32(1/sqrt(32))

  const float* m_p = maps  + b * HW;
  const float* s_p = start + b * HW;
  const float* g_p = goal  + b * HW;

  // ---------------- Phase 1: encoder (lane-contiguous pixel map) -----------
  float acc2[4] = {b2[0], b2[0], b2[0], b2[0]};
  for (int grp = 0; grp < 4; ++grp) {
    #pragma unroll
    for (int p = 0; p < 4; ++p) {
      int pix = p * 256 + t;
      int y = pix >> 5, x = pix & 31;
      float win0[9], win1[9];
      #pragma unroll
      for (int ky = 0; ky < 3; ++ky) {
        #pragma unroll
        for (int kx = 0; kx < 3; ++kx) {
          int yy = y + ky - 1, xx = x + kx - 1;
          bool ok = (yy >= 0) && (yy <= 31) && (xx >= 0) && (xx <= 31);
          int q = ok ? yy * 32 + xx : 0;
          float v0 = m_p[q];
          float v1 = s_p[q] + g_p[q];
          win0[ky * 3 + kx] = ok ? v0 : 0.0f;
          win1[ky * 3 + kx] = ok ? v1 : 0.0f;
        }
      }
      #pragma unroll
      for (int ocl = 0; ocl < 8; ++ocl) {
        int oc = grp * 8 + ocl;
        const float* w = w1 + oc * 18;
        float acc = b1[oc];
        #pragma unroll
        for (int k = 0; k < 9; ++k) {
          acc += win0[k] * w[k];       // same per-pixel op order as round 1
          acc += win1[k] * w[9 + k];
        }
        hid[ocl][pix] = fmaxf(acc, 0.0f);
      }
    }
    __syncthreads();
    #pragma unroll
    for (int p = 0; p < 4; ++p) {
      int pix = p * 256 + t;
      int y = pix >> 5, x = pix & 31;
      float a = acc2[p];
      #pragma unroll
      for (int ocl = 0; ocl < 8; ++ocl) {
        int ic = grp * 8 + ocl;
        const float* w = w2 + ic * 9;
        #pragma unroll
        for (int ky = 0; ky < 3; ++ky) {
          #pragma unroll
          for (int kx = 0; kx < 3; ++kx) {
            int yy = y + ky - 1, xx = x + kx - 1;
            bool ok = (yy >= 0) && (yy <= 31) && (xx >= 0) && (xx <= 31);
            int q = ok ? yy * 32 + xx : 0;
            float hv = hid[ocl][q];
            a += (ok ? hv : 0.0f) * w[ky * 3 + kx];
          }
        }
      }
      acc2[p] = a;
    }
    __syncthreads();
  }
  #pragma unroll
  for (int p = 0; p < 4; ++p) {
    int pix = p * 256 + t;
    float c = 1.0f / (1.0f + expf(-acc2[p]));
    c_l[pix] = c;
    out_cost[b * HW + pix] = c;          // stride-1 across lanes: coalesced
  }
  __syncthreads();

  // ---------------- Phase 2: A* (wave 0, all-register + inc. tree) ---------
  if (t < 64) {
    const int lane = t;
    reinterpret_cast<int4*>(path_sh)[lane] = make_int4(0, 0, 0, 0);
    // goal via ballot (one-hot)
    int myg = -1;
    #pragma unroll
    for (int j = 0; j < 16; ++j) {
      int cell = j * 64 + lane;
      if (g_p[cell] > 0.5f) myg = cell;
    }
    unsigned long long gm = __ballot(myg >= 0);
    int src_lane = (int)__ffsll(gm) - 1;
    const int goal_idx = __shfl(myg, src_lane, 64);
    const int gy = goal_idx >> 5, gx = goal_idx & 31;

    unsigned int open_m = 0, hist_m = 0, obs_m = 0;
    float gr[16], hr[16], cr[16];
    unsigned int vr[16];
    #pragma unroll
    for (int j = 0; j < 16; ++j) {
      int cell = j * 64 + lane;
      int y = cell >> 5, x = cell & 31;
      float cst = c_l[cell];
      cr[j] = cst;
      int dy = y - gy; dy = dy < 0 ? -dy : dy;
      int dx = x - gx; dx = dx < 0 ? -dx : dx;
      float e = sqrtf((float)(dy * dy + dx * dx));
      float heur = __fadd_rn((float)(dy + dx), __fmul_rn(0.001f, e));
      float hc = __fadd_rn(heur, cst);       // h4 = heuristic + cost
      hr[j] = hc;
      gr[j] = 0.0f;
      bool isobs = (m_p[cell] != 0.0f);
      bool isst  = (s_p[cell] > 0.5f);
      if (isobs) obs_m  |= 1u << j;
      if (isst)  open_m |= 1u << j;
      float f = 0.5f * (0.0f + hc);
      float ex = expf(__fmul_rn(-f, C_INV));
      vr[j] = isst ? __float_as_uint(ex) : 0u;
      par[cell] = (unsigned short)goal_idx;
    }

    // build the tournament tree (once)
    unsigned int pv[8], pj[8], qv[4], qj[4], ov[2], oj[2], rv, rj;
    #pragma unroll
    for (int a = 0; a < 8; ++a) PAIR_FIX(a);
    #pragma unroll
    for (int q = 0; q < 4; ++q) QUAD_FIX(q);
    #pragma unroll
    for (int o = 0; o < 2; ++o) OCT_FIX(o);
    ROOT_FIX();

    const int x = lane & 31, half = lane >> 5;
    const unsigned int lowbase = 1023u - (unsigned)lane;  // key = lowbase-64j

    for (int step = 0; step < 256; ++step) {
      // phase A: cross-lane value max (u32 compare == f32 compare, all >=0)
      unsigned int vmx = rv;
      DPPMAX32(vmx, 0x111);  // row_shr:1
      DPPMAX32(vmx, 0x112);  // row_shr:2
      DPPMAX32(vmx, 0x114);  // row_shr:4
      DPPMAX32(vmx, 0x118);  // row_shr:8
      DPPMAX32(vmx, 0x142);  // row_bcast:15
      DPPMAX32(vmx, 0x143);  // row_bcast:31
      const unsigned int svmax =
          (unsigned int)__builtin_amdgcn_readlane((int)vmx, 63);
      // phase B: position key among value-matching lanes (max lo = min cell)
      unsigned int lo = (rv == svmax) ? (lowbase - (rj << 6)) : 0u;
      DPPMAX32(lo, 0x111);
      DPPMAX32(lo, 0x112);
      DPPMAX32(lo, 0x114);
      DPPMAX32(lo, 0x118);
      DPPMAX32(lo, 0x142);
      DPPMAX32(lo, 0x143);
      const unsigned int klo =
          (unsigned int)__builtin_amdgcn_readlane((int)lo, 63);
      const int sel = __builtin_amdgcn_readfirstlane(1023 - (int)klo);
      const int jsel = sel >> 6, owner = sel & 63;
      const int ys = sel >> 5, xs = sel & 31;
      const bool unsolved = (sel != goal_idx);

      // uniform register pair touched this step: {j0, j0+1}
      const int j0 = (ys > 0 ? ys - 1 : 0) >> 1;
      const int jP = (ys < 31 ? ys + 1 : 31) >> 1;     // B-candidate index
      const bool jS_is_j0 = (jsel == j0);
      const bool jP_is_j0 = (jP == j0);

      // per-lane geometry (candidates are always lane-owned cells)
      int dxs = x - xs; int adx = dxs < 0 ? -dxs : dxs;
      const bool act = (adx <= 1);
      const bool samep = (((ys ^ half) & 1) == 0);
      const int yA = samep ? ys : (ys - 1);
      const bool vAv = act && (samep ? (adx >= 1) : (yA >= 0));
      const int yB = ys + 1;
      const bool vBv = act && (!samep) && (yB <= 31);
      const int cA = vAv ? (yA * 32 + x) : 0;
      const int cB = vBv ? (yB * 32 + x) : 0;
      const int vjA = samep ? jsel : j0;               // A-candidate reg idx
      const bool vjA_is_j0 = (!samep) || jS_is_j0;

      bool obA = (obs_m  >> (vjA & 15)) & 1;
      bool opA = (open_m >> (vjA & 15)) & 1;
      bool hiA = (hist_m >> (vjA & 15)) & 1;
      bool obB = (obs_m  >> (jP & 15)) & 1;
      bool opB = (open_m >> (jP & 15)) & 1;
      bool hiB = (hist_m >> (jP & 15)) & 1;
      const bool canAn = vAv && obA && !opA && !hiA;   // new-open path
      const bool canAr = vAv && obA && opA;            // relax path (g>gsum)
      const bool canBn = vBv && obB && !opB && !hiB;
      const bool canBr = vBv && obB && opB;

      const bool ownerlane = (lane == owner);
      const bool closeU = unsolved && ownerlane;
      // change detection (pre-update bits)
      const bool histnew = ownerlane && !((hist_m >> (jsel & 15)) & 1);
      const bool opencl  = closeU && ((open_m >> (jsel & 15)) & 1);

      bool idxA = false, idxB = false;

      // single merged uniform switch: extract + relax + write + tree repair
      #pragma unroll
      for (int j = 0; j < 16; ++j) {
        if (j0 == j) {
          const int jn = (j < 15) ? j + 1 : 15;
          const float gj0 = gr[j],  hj0v = hr[j],  cj0 = cr[j];
          const float gj1 = gr[jn], hj1v = hr[jn], cj1 = cr[jn];
          // uniform reads of the selected cell via owner-lane readlane
          float gselv = jS_is_j0 ? gj0 : gj1;
          float cselv = jS_is_j0 ? cj0 : cj1;
          float gs = __uint_as_float((unsigned int)__builtin_amdgcn_readlane(
              (int)__float_as_uint(gselv), owner));
          float cs = __uint_as_float((unsigned int)__builtin_amdgcn_readlane(
              (int)__float_as_uint(cselv), owner));
          const float gsum = gs + cs;        // g2 value (exact, as reference)

          const float gA = vjA_is_j0 ? gj0 : gj1;
          const float hA = vjA_is_j0 ? hj0v : hj1v;
          const float gB = jP_is_j0 ? gj0 : gj1;
          const float hB = jP_is_j0 ? hj0v : hj1v;
          idxA = canAn || (canAr && (gA > gsum));
          idxB = canBn || (canBr && (gB > gsum));

          // new key values (identical FP sequence to previous rounds)
          float fA = 0.5f * (gsum + hA);
          unsigned int nvA = __float_as_uint(expf(__fmul_rn(-fA, C_INV)));
          float fB = 0.5f * (gsum + hB);
          unsigned int nvB = __float_as_uint(expf(__fmul_rn(-fB, C_INV)));

          // register writes (A and B are mutually exclusive per lane)
          const bool uA0 = idxA && vjA_is_j0, uB0 = idxB && jP_is_j0;
          const bool uA1 = idxA && !vjA_is_j0, uB1 = idxB && !jP_is_j0;
          const bool u0 = uA0 || uB0, u1 = uA1 || uB1;
          if (u0) { gr[j]  = gsum; vr[j]  = uA0 ? nvA : nvB; }
          if (u1) { gr[jn] = gsum; vr[jn] = uA1 ? nvA : nvB; }
          // close selected cell (owner lane never relaxes its own cells)
          if (closeU &&  jS_is_j0) vr[j]  = 0u;
          if (closeU && !jS_is_j0) vr[jn] = 0u;

          // incremental tree repair along leaves {j, jn} (static indices)
          const int pa = j >> 1, pb = jn >> 1;
          PAIR_FIX(pa);
          if (pb != pa) PAIR_FIX(pb);
          const int qa = pa >> 1, qb = pb >> 1;
          QUAD_FIX(qa);
          if (qb != qa) QUAD_FIX(qb);
          const int oa = qa >> 1, ob = qb >> 1;
          OCT_FIX(oa);
          if (ob != oa) OCT_FIX(ob);
          ROOT_FIX();
        }
      }

      // par stays in LDS: write-only inside the loop, never waited on
      if (idxA) par[cA] = (unsigned short)sel;
      if (idxB) par[cB] = (unsigned short)sel;

      // mask updates
      hist_m |= ownerlane ? (1u << (jsel & 15)) : 0u;
      unsigned int clr = closeU ? (1u << (jsel & 15)) : 0u;
      unsigned int aA  = idxA ? (1u << (vjA & 15)) : 0u;
      unsigned int aB  = idxB ? (1u << (jP & 15)) : 0u;
      open_m = (open_m & ~clr) | aA | aB;

      // freeze: nothing changed => fixed point => all remaining steps no-ops
      unsigned long long anych = __ballot(idxA || idxB || histnew || opencl);
      if (anych == 0ull) break;
    }

    hist_lds[lane] = hist_m;

    // backtrack (parent table static; revisit => cycle => exact early exit)
    if (lane == 0) {
      path_sh[goal_idx] = 1;
      int loc = par[goal_idx];
      for (int i = 0; i < 255; ++i) {
        if (path_sh[loc]) break;
        path_sh[loc] = 1;
        loc = par[loc];
      }
    }
  }
  __syncthreads();

  // ---------------- Phase 3: outputs ----------------
  const int base = t * 4;
  float hv[4], pvv[4];
  #pragma unroll
  for (int p = 0; p < 4; ++p) {
    int cell = base + p;
    hv[p] = (float)((hist_lds[cell & 63] >> (cell >> 6)) & 1);
    pvv[p] = (float)path_sh[cell];
  }
  *reinterpret_cast<float4*>(out_hist + b * HW + base) =
      make_float4(hv[0], hv[1], hv[2], hv[3]);
  *reinterpret_cast<float4*>(out_path + b * HW + base) =
      make_float4(pvv[0], pvv[1], pvv[2], pvv[3]);
}

extern "C" void kernel_launch(void* const* d_in, const int* in_sizes, int n_in,
                              void* d_out, int out_size, void* d_ws, size_t ws_size,
                              hipStream_t stream) {
  (void)in_sizes; (void)n_in; (void)d_ws; (void)ws_size; (void)out_size;
  const float* maps  = (const float*)d_in[0];
  const float* start = (const float*)d_in[1];
  const float* goal  = (const float*)d_in[2];
  const float* w1    = (const float*)d_in[3];
  const float* b1    = (const float*)d_in[4];
  const float* w2    = (const float*)d_in[5];
  const float* b2    = (const float*)d_in[6];

  float* out      = (float*)d_out;
  float* out_hist = out;
  float* out_path = out + 64 * HW;
  float* out_cost = out + 128 * HW;

  fused_nastar<<<64, 256, 0, stream>>>(maps, start, goal, w1, b1, w2, b2,
                                       out_hist, out_path, out_cost);
}